// Round 12
// baseline (902.487 us; speedup 1.0000x reference)
//
#include <hip/hip_runtime.h>
#include <math.h>

// ===== INSTRUMENTATION ROUND: scores and pool bodies looped REPEAT=8x =====
// Output is identical (idempotent reps); dur_us decodes per-kernel times:
//   S + P = (dur - 138.8us)/7 ; visible top-5 dispatch gives 8S or 8P exactly.

#define NN 500000
#define CH 128
#define NG 1024
#define GRID_S 512
#define TILES ((NN + 127) >> 7)
#define REPEAT 8

typedef __attribute__((ext_vector_type(8))) short short8v;
typedef __attribute__((ext_vector_type(4))) float f32x4;

__device__ __forceinline__ void bf16_split(float f, unsigned short& h, unsigned short& l){
  const unsigned u = __float_as_uint(f);
  h = (unsigned short)(u >> 16);
  const float hif = __uint_as_float(u & 0xffff0000u);
  const float lof = f - hif;
  l = (unsigned short)(__float_as_uint(lof) >> 16);
}

__device__ __forceinline__ void gld_lds16(const void* g, void* l){
  __builtin_amdgcn_global_load_lds(
      (__attribute__((address_space(1))) void*)g,
      (__attribute__((address_space(3))) void*)l, 16, 0, 0);
}

__device__ __forceinline__ void cvt8(const float4 f0, const float4 f1,
                                     short8v& Ah, short8v& Al){
  float fv[8];
  *reinterpret_cast<float4*>(fv) = f0;
  *reinterpret_cast<float4*>(fv + 4) = f1;
  unsigned short hv[8], lv[8];
  #pragma unroll
  for (int j = 0; j < 8; j++) bf16_split(fv[j], hv[j], lv[j]);
  Ah = *reinterpret_cast<short8v*>(hv);
  Al = *reinterpret_cast<short8v*>(lv);
}

__global__ __launch_bounds__(256) void prep_kernel(
    const float* __restrict__ W1, unsigned short* __restrict__ Wg,
    const int* __restrict__ batch, int* __restrict__ start){
  const int t = blockIdx.x * 256 + threadIdx.x;
  if (t < 2048){
    const int n  = t >> 4;
    const int k0 = (t & 15) << 3;
    unsigned short hv[8], lv[8];
    #pragma unroll
    for (int i = 0; i < 8; i++)
      bf16_split(W1[(size_t)(k0 + i) * CH + n], hv[i], lv[i]);
    *reinterpret_cast<short8v*>(Wg + n * 128 + k0) = *reinterpret_cast<short8v*>(hv);
    *reinterpret_cast<short8v*>(Wg + 16384 + n * 128 + k0) = *reinterpret_cast<short8v*>(lv);
  } else if (t <= 2048 + NG){
    const int g = t - 2048;
    const bool is64 = (batch[NN - 1] == 0);
    if (g == NG){ start[NG] = NN; return; }
    int lo = 0, hi = NN;
    while (lo < hi){
      int mid = (lo + hi) >> 1;
      int v = is64 ? batch[2 * mid] : batch[mid];
      if (v < g) lo = mid + 1; else hi = mid;
    }
    start[g] = lo;
  }
}

__global__ __launch_bounds__(512, 4) void scores_mfma(
    const float* __restrict__ x, const unsigned short* __restrict__ Wg,
    const float* __restrict__ b1, const float* __restrict__ w2,
    const float* __restrict__ b2, float* __restrict__ escore)
{
  __shared__ char  XS[4 * 16384];
  __shared__ float p4[4][128];
  __shared__ float b1s[CH], w2s[CH];

  const int tid = threadIdx.x;
  const int w   = tid >> 6;
  const int l   = tid & 63;
  const int l15 = l & 15;
  const int g   = l >> 4;
  const int rw  = w & 1;
  const int cw  = w >> 1;

  const int bid = blockIdx.x;
  const int ntb = (TILES - 1 - bid) / GRID_S + 1;
  const int NP  = ntb * 4;
  const float b2v = b2[0];

  if (tid < CH){ b1s[tid] = b1[tid]; w2s[tid] = w2[tid]; }

  short8v Bf[2][4][2];
  #pragma unroll
  for (int ctk = 0; ctk < 2; ++ctk){
    const int n = (cw * 2 + ctk) * 16 + l15;
    #pragma unroll
    for (int kc = 0; kc < 4; ++kc){
      Bf[ctk][kc][0] = *reinterpret_cast<const short8v*>(Wg + n * 128 + kc * 32 + g * 8);
      Bf[ctk][kc][1] = *reinterpret_cast<const short8v*>(Wg + 16384 + n * 128 + kc * 32 + g * 8);
    }
  }

  int srcoff[2], dstoff[2];
  #pragma unroll
  for (int p = 0; p < 2; ++p){
    const int idx = p * 512 + tid;
    const int R = idx >> 3, c = idx & 7;
    srcoff[p] = R * 512 + ((c ^ (R & 7)) << 4);
    dstoff[p] = idx * 16;
  }
  auto stage = [&](int SL){
    char* base = XS + (SL & 3) * 16384;
    const size_t tb = (size_t)(bid + (SL >> 2) * GRID_S) * 65536 + (SL & 3) * 128;
    #pragma unroll
    for (int p = 0; p < 2; ++p){
      size_t so = tb + srcoff[p];
      if (so >= (size_t)NN * 512) so = (size_t)(NN - 1) * 512;
      gld_lds16((const char*)x + so, base + dstoff[p]);
    }
  };

  const int abase = (rw * 64 + l15) * 128;
  const int sw0 = ((2 * g)     ^ (l15 & 7)) << 4;
  const int sw1 = ((2 * g + 1) ^ (l15 & 7)) << 4;

  for (int rep = 0; rep < REPEAT; ++rep){
    stage(0); stage(1);
    asm volatile("s_waitcnt vmcnt(0) lgkmcnt(0)" ::: "memory");
    __syncthreads();

    for (int ti = 0; ti < ntb; ++ti){
      const int tilebase = (bid + ti * GRID_S) * 128;

      f32x4 acc[4][2];
      #pragma unroll
      for (int a = 0; a < 4; ++a)
        #pragma unroll
        for (int b = 0; b < 2; ++b) acc[a][b] = (f32x4)0.f;

      #pragma unroll
      for (int ks = 0; ks < 4; ++ks){
        const int P = ti * 4 + ks;
        if (ti == ntb - 1 && ks == 3)
          asm volatile("s_waitcnt vmcnt(0)" ::: "memory");
        else if (ks <= 1 && w < 2 && ti > 0)
          asm volatile("s_waitcnt vmcnt(3)" ::: "memory");
        else
          asm volatile("s_waitcnt vmcnt(2)" ::: "memory");
        __builtin_amdgcn_s_barrier();
        if (P + 2 < NP) stage(P + 2);

        const char* sb = XS + ks * 16384;
        #pragma unroll
        for (int nt = 0; nt < 4; ++nt){
          const char* bp = sb + abase + nt * 2048;
          short8v Ah, Al;
          cvt8(*reinterpret_cast<const float4*>(bp + sw0),
               *reinterpret_cast<const float4*>(bp + sw1), Ah, Al);
          #pragma unroll
          for (int ctk = 0; ctk < 2; ++ctk){
            acc[nt][ctk] = __builtin_amdgcn_mfma_f32_16x16x32_bf16(Ah, Bf[ctk][ks][0], acc[nt][ctk], 0, 0, 0);
            acc[nt][ctk] = __builtin_amdgcn_mfma_f32_16x16x32_bf16(Al, Bf[ctk][ks][0], acc[nt][ctk], 0, 0, 0);
            acc[nt][ctk] = __builtin_amdgcn_mfma_f32_16x16x32_bf16(Ah, Bf[ctk][ks][1], acc[nt][ctk], 0, 0, 0);
          }
        }
      }

      const float b1v0 = b1s[cw * 32 + l15], b1v1 = b1s[cw * 32 + 16 + l15];
      const float w2v0 = w2s[cw * 32 + l15], w2v1 = w2s[cw * 32 + 16 + l15];
      #pragma unroll
      for (int nt = 0; nt < 4; ++nt){
        #pragma unroll
        for (int r = 0; r < 4; ++r){
          float s = fmaxf(acc[nt][0][r] + b1v0, 0.f) * w2v0;
          s = fmaf(fmaxf(acc[nt][1][r] + b1v1, 0.f), w2v1, s);
          s += __shfl_xor(s, 1); s += __shfl_xor(s, 2);
          s += __shfl_xor(s, 4); s += __shfl_xor(s, 8);
          if (l15 == 0) p4[cw][rw * 64 + nt * 16 + g * 4 + r] = s;
        }
      }
      asm volatile("s_waitcnt lgkmcnt(0)" ::: "memory");
      __builtin_amdgcn_s_barrier();
      if (tid < 128){
        const float s = p4[0][tid] + p4[1][tid] + p4[2][tid] + p4[3][tid] + b2v;
        const int grow = tilebase + tid;
        if (grow < NN) escore[grow] = __expf(s);
      }
    }
    // drain before next rep so per-rep vmcnt bookkeeping restarts clean
    asm volatile("s_waitcnt vmcnt(0)" ::: "memory");
    __syncthreads();
  }
}

__global__ __launch_bounds__(512) void pool_kernel(
    const float* __restrict__ x, const float* __restrict__ es,
    const int* __restrict__ start, float* __restrict__ out){
  const int g = blockIdx.x;
  const int s0 = start[g], s1 = start[g + 1];
  const int tid = threadIdx.x;
  const int c4 = tid & 31;
  const int rg = tid >> 5;

  __shared__ float4 red[16][32];
  __shared__ float redd[16][32];

  for (int rep = 0; rep < REPEAT; ++rep){
    float4 a0 = make_float4(0.f, 0.f, 0.f, 0.f);
    float4 a1 = make_float4(0.f, 0.f, 0.f, 0.f);
    float d0 = 0.f, d1 = 0.f;
    int i = s0 + rg;
    for (; i + 16 < s1; i += 32){
      const float e0 = es[i];
      const float e1 = es[i + 16];
      const float4 v0 = reinterpret_cast<const float4*>(&x[(size_t)i * CH])[c4];
      const float4 v1 = reinterpret_cast<const float4*>(&x[(size_t)(i + 16) * CH])[c4];
      a0.x = fmaf(e0, v0.x, a0.x); a0.y = fmaf(e0, v0.y, a0.y);
      a0.z = fmaf(e0, v0.z, a0.z); a0.w = fmaf(e0, v0.w, a0.w);
      d0 += e0;
      a1.x = fmaf(e1, v1.x, a1.x); a1.y = fmaf(e1, v1.y, a1.y);
      a1.z = fmaf(e1, v1.z, a1.z); a1.w = fmaf(e1, v1.w, a1.w);
      d1 += e1;
    }
    if (i < s1){
      const float e0 = es[i];
      const float4 v0 = reinterpret_cast<const float4*>(&x[(size_t)i * CH])[c4];
      a0.x = fmaf(e0, v0.x, a0.x); a0.y = fmaf(e0, v0.y, a0.y);
      a0.z = fmaf(e0, v0.z, a0.z); a0.w = fmaf(e0, v0.w, a0.w);
      d0 += e0;
    }
    a0.x += a1.x; a0.y += a1.y; a0.z += a1.z; a0.w += a1.w;
    d0 += d1;

    red[rg][c4] = a0;
    redd[rg][c4] = d0;
    __syncthreads();
    if (rg < 8){
      float4 o = red[rg + 8][c4], m = red[rg][c4];
      m.x += o.x; m.y += o.y; m.z += o.z; m.w += o.w;
      red[rg][c4] = m;
      redd[rg][c4] += redd[rg + 8][c4];
    }
    __syncthreads();
    if (rg < 4){
      float4 o = red[rg + 4][c4], m = red[rg][c4];
      m.x += o.x; m.y += o.y; m.z += o.z; m.w += o.w;
      red[rg][c4] = m;
      redd[rg][c4] += redd[rg + 4][c4];
    }
    __syncthreads();
    if (rg < 2){
      float4 o = red[rg + 2][c4], m = red[rg][c4];
      m.x += o.x; m.y += o.y; m.z += o.z; m.w += o.w;
      red[rg][c4] = m;
      redd[rg][c4] += redd[rg + 2][c4];
    }
    __syncthreads();
    if (rg == 0){
      float4 b0 = red[0][c4], b1v = red[1][c4];
      const float d = redd[0][c4] + redd[1][c4];
      const float inv = d > 0.f ? 1.f / d : 0.f;
      float4 r;
      r.x = (b0.x + b1v.x) * inv; r.y = (b0.y + b1v.y) * inv;
      r.z = (b0.z + b1v.z) * inv; r.w = (b0.w + b1v.w) * inv;
      reinterpret_cast<float4*>(&out[(size_t)g * CH])[c4] = r;
    }
    __syncthreads();   // red/redd safe for next rep
  }
}

extern "C" void kernel_launch(void* const* d_in, const int* in_sizes, int n_in,
                              void* d_out, int out_size, void* d_ws, size_t ws_size,
                              hipStream_t stream){
  const float* x    = (const float*)d_in[0];
  const int*   batch= (const int*)d_in[1];
  const float* W1   = (const float*)d_in[2];
  const float* b1   = (const float*)d_in[3];
  const float* w2   = (const float*)d_in[4];
  const float* b2   = (const float*)d_in[5];
  float* out = (float*)d_out;

  float* es    = (float*)d_ws;
  int*   start = (int*)((char*)d_ws + (size_t)NN * sizeof(float));
  unsigned short* Wg = (unsigned short*)((char*)d_ws + ((ws_size - 65536) & ~(size_t)255));

  prep_kernel<<<13, 256, 0, stream>>>(W1, Wg, batch, start);
  scores_mfma<<<GRID_S, 512, 0, stream>>>(x, Wg, b1, w2, b2, es);
  pool_kernel<<<NG, 512, 0, stream>>>(x, es, start, out);
}

// Round 13
// 133.699 us; speedup vs baseline: 6.7501x; 6.7501x over previous
//
#include <hip/hip_runtime.h>
#include <math.h>

#define NN 500000
#define CH 128
#define NG 1024
#define GRID_S 512
#define TILES ((NN + 127) >> 7)   // 3907 tiles of 128 rows

typedef __attribute__((ext_vector_type(8))) short short8v;
typedef __attribute__((ext_vector_type(4))) float f32x4;

__device__ __forceinline__ void bf16_split(float f, unsigned short& h, unsigned short& l){
  const unsigned u = __float_as_uint(f);
  h = (unsigned short)(u >> 16);
  const float hif = __uint_as_float(u & 0xffff0000u);
  const float lof = f - hif;
  l = (unsigned short)(__float_as_uint(lof) >> 16);
}

// Prep: (a) t<2048: transpose + bf16-hi/lo-split W1 into Wg, LINEAR layout:
// hi[n][k] at Wg + n*128 + k, lo at +16384 (ushort units).
// (b) t in [2048, 2048+NG]: segment boundaries via lower_bound on sorted batch.
__global__ __launch_bounds__(256) void prep_kernel(
    const float* __restrict__ W1, unsigned short* __restrict__ Wg,
    const int* __restrict__ batch, int* __restrict__ start){
  const int t = blockIdx.x * 256 + threadIdx.x;
  if (t < 2048){
    const int n  = t >> 4;
    const int k0 = (t & 15) << 3;
    unsigned short hv[8], lv[8];
    #pragma unroll
    for (int i = 0; i < 8; i++)
      bf16_split(W1[(size_t)(k0 + i) * CH + n], hv[i], lv[i]);
    *reinterpret_cast<short8v*>(Wg + n * 128 + k0) = *reinterpret_cast<short8v*>(hv);
    *reinterpret_cast<short8v*>(Wg + 16384 + n * 128 + k0) = *reinterpret_cast<short8v*>(lv);
  } else if (t <= 2048 + NG){
    const int g = t - 2048;
    const bool is64 = (batch[NN - 1] == 0);   // int64-vs-int32 runtime hedge
    if (g == NG){ start[NG] = NN; return; }
    int lo = 0, hi = NN;
    while (lo < hi){
      int mid = (lo + hi) >> 1;
      int v = is64 ? batch[2 * mid] : batch[mid];
      if (v < g) lo = mid + 1; else hi = mid;
    }
    start[g] = lo;
  }
}

// K1: escore[n] = exp(relu(x[n]@W1 + b1).w2 + b2), 3-term bf16-split MFMA.
// Reg-staged conversion SHARED via LDS: each thread converts its unique 8 f32
// per slice (4x less VALU than per-wave conversion), writes bf16 hi|lo panes;
// all waves ds_read MFMA fragments directly. W in registers. 2 slots x 16KB.
// Swizzle (both sides): chunk' = chunk ^ ((R>>1)&3)  -> balanced banks.
__global__ __launch_bounds__(512, 4) void scores_mfma(
    const float* __restrict__ x, const unsigned short* __restrict__ Wg,
    const float* __restrict__ b1, const float* __restrict__ w2,
    const float* __restrict__ b2, float* __restrict__ escore)
{
  __shared__ char  XS[2 * 16384];   // slot: hi 8KB | lo 8KB (128r x 32k bf16)
  __shared__ float p4[4][128];      // per-ch-quarter partial w2-dots
  __shared__ float b1s[CH], w2s[CH];

  const int tid = threadIdx.x;
  const int w   = tid >> 6;     // wave 0..7
  const int l   = tid & 63;
  const int l15 = l & 15;
  const int g   = l >> 4;       // 0..3
  const int rw  = w & 1;        // row half (64 rows)
  const int cw  = w >> 1;       // ch quarter (32 ch)

  const int bid = blockIdx.x;
  const int ntb = (TILES - 1 - bid) / GRID_S + 1;
  const int NP  = ntb * 4;
  const float b2v = b2[0];

  if (tid < CH){ b1s[tid] = b1[tid]; w2s[tid] = w2[tid]; }

  // W fragments -> registers, constant across tiles.
  short8v Bf[2][4][2];
  #pragma unroll
  for (int ctk = 0; ctk < 2; ++ctk){
    const int n = (cw * 2 + ctk) * 16 + l15;
    #pragma unroll
    for (int kc = 0; kc < 4; ++kc){
      Bf[ctk][kc][0] = *reinterpret_cast<const short8v*>(Wg + n * 128 + kc * 32 + g * 8);
      Bf[ctk][kc][1] = *reinterpret_cast<const short8v*>(Wg + 16384 + n * 128 + kc * 32 + g * 8);
    }
  }

  // Staging geometry: thread t -> row Rs = t>>2, k-chunk gw = t&3 (8 f32 = 32B).
  const int Rs = tid >> 2, gw = tid & 3;
  const int wbyte = Rs * 64 + ((gw ^ ((Rs >> 1) & 3)) << 4);   // in hi pane
  // A-read geometry: R = rw*64 + nt*16 + l15; (R>>1)&3 = (l15>>1)&3 (nt-indep).
  const int rbyte0 = (rw * 64 + l15) * 64 + (((g ^ ((l15 >> 1) & 3))) << 4);

  // Load slice (tile ti2, k-slice ks2) into dst regs (static buffer ref!).
  auto issue = [&](float4* dst, int ti2, int ks2){
    int row = (bid + ti2 * GRID_S) * 128 + Rs;
    row = row < NN ? row : NN - 1;   // clamp; es store guarded
    const float4* src = reinterpret_cast<const float4*>(
        (const char*)x + (size_t)row * 512 + ks2 * 128 + gw * 32);
    dst[0] = src[0];
    dst[1] = src[1];
  };

  float4 stg[2][2];                  // [slice parity][2 float4]
  issue(stg[0], 0, 0);
  issue(stg[1], 0, 1);

  for (int ti = 0; ti < ntb; ++ti){
    const int tilebase = (bid + ti * GRID_S) * 128;

    f32x4 acc[4][2];
    #pragma unroll
    for (int a = 0; a < 4; ++a)
      #pragma unroll
      for (int b = 0; b < 2; ++b) acc[a][b] = (f32x4)0.f;

    #pragma unroll
    for (int ks = 0; ks < 4; ++ks){
      const int P = ti * 4 + ks;

      // Convert this slice (compiler inserts the exact vmcnt wait for stg).
      {
        float fv[8];
        *reinterpret_cast<float4*>(fv)     = stg[ks & 1][0];
        *reinterpret_cast<float4*>(fv + 4) = stg[ks & 1][1];
        unsigned hq[4], lq[4];
        #pragma unroll
        for (int j = 0; j < 4; ++j){
          const unsigned u0 = __float_as_uint(fv[2 * j]);
          const unsigned u1 = __float_as_uint(fv[2 * j + 1]);
          hq[j] = (u0 >> 16) | (u1 & 0xffff0000u);
          const float l0 = fv[2 * j]     - __uint_as_float(u0 & 0xffff0000u);
          const float l1 = fv[2 * j + 1] - __uint_as_float(u1 & 0xffff0000u);
          lq[j] = (__float_as_uint(l0) >> 16) | (__float_as_uint(l1) & 0xffff0000u);
        }
        char* pane = XS + (ks & 1) * 16384;
        *reinterpret_cast<uint4*>(pane + wbyte)        = make_uint4(hq[0], hq[1], hq[2], hq[3]);
        *reinterpret_cast<uint4*>(pane + 8192 + wbyte) = make_uint4(lq[0], lq[1], lq[2], lq[3]);
      }
      // Prefetch slice P+2 into the buffer just consumed (data dep orders it).
      if (P + 2 < NP) issue(stg[ks & 1], (P + 2) >> 2, (ks + 2) & 3);

      asm volatile("s_waitcnt lgkmcnt(0)" ::: "memory");
      __builtin_amdgcn_s_barrier();
      asm volatile("" ::: "memory");   // pin reads below barrier

      // MFMA: fragments straight from bf16 panes (no conversion).
      const char* ph = XS + (ks & 1) * 16384;
      #pragma unroll
      for (int nt = 0; nt < 4; ++nt){
        const short8v Ah = *reinterpret_cast<const short8v*>(ph + rbyte0 + nt * 1024);
        const short8v Al = *reinterpret_cast<const short8v*>(ph + 8192 + rbyte0 + nt * 1024);
        #pragma unroll
        for (int ctk = 0; ctk < 2; ++ctk){
          acc[nt][ctk] = __builtin_amdgcn_mfma_f32_16x16x32_bf16(Ah, Bf[ctk][ks][0], acc[nt][ctk], 0, 0, 0);
          acc[nt][ctk] = __builtin_amdgcn_mfma_f32_16x16x32_bf16(Al, Bf[ctk][ks][0], acc[nt][ctk], 0, 0, 0);
          acc[nt][ctk] = __builtin_amdgcn_mfma_f32_16x16x32_bf16(Ah, Bf[ctk][ks][1], acc[nt][ctk], 0, 0, 0);
        }
      }
    }

    // Epilogue: s = relu(H+b1).w2 partial dots -> p4; 128 threads finish+store.
    const float b1v0 = b1s[cw * 32 + l15], b1v1 = b1s[cw * 32 + 16 + l15];
    const float w2v0 = w2s[cw * 32 + l15], w2v1 = w2s[cw * 32 + 16 + l15];
    #pragma unroll
    for (int nt = 0; nt < 4; ++nt){
      #pragma unroll
      for (int r = 0; r < 4; ++r){
        float s = fmaxf(acc[nt][0][r] + b1v0, 0.f) * w2v0;
        s = fmaf(fmaxf(acc[nt][1][r] + b1v1, 0.f), w2v1, s);
        s += __shfl_xor(s, 1); s += __shfl_xor(s, 2);
        s += __shfl_xor(s, 4); s += __shfl_xor(s, 8);
        if (l15 == 0) p4[cw][rw * 64 + nt * 16 + g * 4 + r] = s;
      }
    }
    asm volatile("s_waitcnt lgkmcnt(0)" ::: "memory");
    __builtin_amdgcn_s_barrier();
    asm volatile("" ::: "memory");
    if (tid < 128){
      const float s = p4[0][tid] + p4[1][tid] + p4[2][tid] + p4[3][tid] + b2v;
      const int grow = tilebase + tid;
      if (grow < NN) escore[grow] = __expf(s);
    }
    // next tile's first phase barrier separates p4 reuse
  }
}

// Pool: out[g][c] = sum_i es[i]*x[i][c] / sum_i es[i]. 512 thr, 2 chains.
__global__ __launch_bounds__(512) void pool_kernel(
    const float* __restrict__ x, const float* __restrict__ es,
    const int* __restrict__ start, float* __restrict__ out){
  const int g = blockIdx.x;
  const int s0 = start[g], s1 = start[g + 1];
  const int tid = threadIdx.x;
  const int c4 = tid & 31;
  const int rg = tid >> 5;

  float4 a0 = make_float4(0.f, 0.f, 0.f, 0.f);
  float4 a1 = make_float4(0.f, 0.f, 0.f, 0.f);
  float d0 = 0.f, d1 = 0.f;
  int i = s0 + rg;
  for (; i + 16 < s1; i += 32){
    const float e0 = es[i];
    const float e1 = es[i + 16];
    const float4 v0 = reinterpret_cast<const float4*>(&x[(size_t)i * CH])[c4];
    const float4 v1 = reinterpret_cast<const float4*>(&x[(size_t)(i + 16) * CH])[c4];
    a0.x = fmaf(e0, v0.x, a0.x); a0.y = fmaf(e0, v0.y, a0.y);
    a0.z = fmaf(e0, v0.z, a0.z); a0.w = fmaf(e0, v0.w, a0.w);
    d0 += e0;
    a1.x = fmaf(e1, v1.x, a1.x); a1.y = fmaf(e1, v1.y, a1.y);
    a1.z = fmaf(e1, v1.z, a1.z); a1.w = fmaf(e1, v1.w, a1.w);
    d1 += e1;
  }
  if (i < s1){
    const float e0 = es[i];
    const float4 v0 = reinterpret_cast<const float4*>(&x[(size_t)i * CH])[c4];
    a0.x = fmaf(e0, v0.x, a0.x); a0.y = fmaf(e0, v0.y, a0.y);
    a0.z = fmaf(e0, v0.z, a0.z); a0.w = fmaf(e0, v0.w, a0.w);
    d0 += e0;
  }
  a0.x += a1.x; a0.y += a1.y; a0.z += a1.z; a0.w += a1.w;
  d0 += d1;

  __shared__ float4 red[16][32];
  __shared__ float redd[16][32];
  red[rg][c4] = a0;
  redd[rg][c4] = d0;
  __syncthreads();
  if (rg < 8){
    float4 o = red[rg + 8][c4], m = red[rg][c4];
    m.x += o.x; m.y += o.y; m.z += o.z; m.w += o.w;
    red[rg][c4] = m;
    redd[rg][c4] += redd[rg + 8][c4];
  }
  __syncthreads();
  if (rg < 4){
    float4 o = red[rg + 4][c4], m = red[rg][c4];
    m.x += o.x; m.y += o.y; m.z += o.z; m.w += o.w;
    red[rg][c4] = m;
    redd[rg][c4] += redd[rg + 4][c4];
  }
  __syncthreads();
  if (rg < 2){
    float4 o = red[rg + 2][c4], m = red[rg][c4];
    m.x += o.x; m.y += o.y; m.z += o.z; m.w += o.w;
    red[rg][c4] = m;
    redd[rg][c4] += redd[rg + 2][c4];
  }
  __syncthreads();
  if (rg == 0){
    float4 b0 = red[0][c4], b1v = red[1][c4];
    const float d = redd[0][c4] + redd[1][c4];
    const float inv = d > 0.f ? 1.f / d : 0.f;
    float4 r;
    r.x = (b0.x + b1v.x) * inv; r.y = (b0.y + b1v.y) * inv;
    r.z = (b0.z + b1v.z) * inv; r.w = (b0.w + b1v.w) * inv;
    reinterpret_cast<float4*>(&out[(size_t)g * CH])[c4] = r;
  }
}

extern "C" void kernel_launch(void* const* d_in, const int* in_sizes, int n_in,
                              void* d_out, int out_size, void* d_ws, size_t ws_size,
                              hipStream_t stream){
  const float* x    = (const float*)d_in[0];
  const int*   batch= (const int*)d_in[1];
  const float* W1   = (const float*)d_in[2];
  const float* b1   = (const float*)d_in[3];
  const float* w2   = (const float*)d_in[4];
  const float* b2   = (const float*)d_in[5];
  float* out = (float*)d_out;

  float* es    = (float*)d_ws;                                      // NN floats
  int*   start = (int*)((char*)d_ws + (size_t)NN * sizeof(float));  // NG+1 ints
  unsigned short* Wg = (unsigned short*)((char*)d_ws + ((ws_size - 65536) & ~(size_t)255));

  prep_kernel<<<13, 256, 0, stream>>>(W1, Wg, batch, start);
  scores_mfma<<<GRID_S, 512, 0, stream>>>(x, Wg, b1, w2, b2, es);
  pool_kernel<<<NG, 512, 0, stream>>>(x, es, start, out);
}